// Round 14
// baseline (186.060 us; speedup 1.0000x reference)
//
#include <hip/hip_runtime.h>
#include <math.h>

#define SEQ 50
#define UNITD 46
#define NEGBIG 1000000000000.0f

typedef _Float16 f16;
typedef f16 f16x4 __attribute__((ext_vector_type(4)));
typedef f16 f16x8 __attribute__((ext_vector_type(8)));
typedef float f32x4 __attribute__((ext_vector_type(4)));
typedef unsigned u32x2 __attribute__((ext_vector_type(2)));
typedef unsigned u32x4 __attribute__((ext_vector_type(4)));

__device__ __forceinline__ float rcpf(float x) { return __builtin_amdgcn_rcpf(x); }
__device__ __forceinline__ unsigned pk2(float lo, float hi) {
    return __builtin_bit_cast(unsigned, __builtin_amdgcn_cvt_pkrtz(lo, hi));
}

// ---- DPP cross-lane moves (VALU pipe, no DS-pipe cost) ----
template<int CTRL>
__device__ __forceinline__ float dmov(float x) {
    int v = __builtin_bit_cast(int, x);
    return __builtin_bit_cast(float, __builtin_amdgcn_update_dpp(v, v, CTRL, 0xF, 0xF, true));
}
__device__ __forceinline__ float dsum16(float x) {   // reduce over each 16-lane row
    x += dmov<0xB1>(x);    // lane^1
    x += dmov<0x4E>(x);    // lane^2
    x += dmov<0x141>(x);   // row_half_mirror
    x += dmov<0x140>(x);   // row_mirror
    return x;
}
__device__ __forceinline__ float dmax16(float x) {
    x = fmaxf(x, dmov<0xB1>(x));  x = fmaxf(x, dmov<0x4E>(x));
    x = fmaxf(x, dmov<0x141>(x)); x = fmaxf(x, dmov<0x140>(x));
    return x;
}

// ---- per-wave arena (bytes) — R10 layout ----
// [0,6400)      P tile [50][128B] swizzled; Q/K overlay early; z[64] f16 overlays [0,128) at end
// [6400,12544)  V^T [48][128B] swizzled (row=u, col=seq)
// [12544,12800) M [64] f32 (mask, zero-padded)
#define ARENA 12800
#define QOFF 0
#define KOFF 2560
#define VOFF 6400
#define MOFF 12544

__device__ __forceinline__ int swzP(int row, int colbyte) {
    return row * 128 + (colbyte ^ ((row & 7) << 4));
}
__device__ __forceinline__ int swzV(int row, int colbyte) {
    return VOFF + row * 128 + (colbyte ^ ((row & 7) << 4));
}

// ---- ws layout ----
// f16x8 units [0,512): Wi B-frags; [512,896): Wo A-frags  (bytes [0,14336))
// bytes [14336,22528): rope table float2[64*16] = (cos*0.5, sgn*sin*0.5)
// bytes [22528,22784): wv float[64] = Wo^T·Wq (zero-padded); [22784]: c0 = bo·Wq+bq
#define WS_ROPE 14336
#define WS_WV   22528
#define WS_C0   22784

__global__ void prep_kernel(const float* __restrict__ Wi,
                            const float* __restrict__ Wo,
                            const float* __restrict__ Wq,
                            const float* __restrict__ bo,
                            const float* __restrict__ bq,
                            char* __restrict__ ws)
{
    f16x8* wf = (f16x8*)ws;
    const int lane = threadIdx.x & 63;
    const int g = lane >> 4, t = lane & 15;
    #pragma unroll
    for (int nt = 0; nt < 4; ++nt) {
        int c = t + 16 * nt; bool cok = c < 62;
        const float* wr = Wi + (size_t)(UNITD + (cok ? c : 0)) * UNITD;
        #pragma unroll
        for (int kt = 0; kt < 2; ++kt) {
            f16x8 f;
            #pragma unroll
            for (int jj = 0; jj < 8; ++jj) {
                int u = 32 * kt + 8 * g + jj;
                f[jj] = (f16)((cok && u < UNITD) ? wr[u] : 0.f);
            }
            wf[(nt * 2 + kt) * 64 + lane] = f;
        }
    }
    #pragma unroll
    for (int mo = 0; mo < 3; ++mo) {
        int o = 16 * mo + t; bool ook = o < UNITD;
        const float* wr = Wo + (size_t)(ook ? o : 0) * UNITD;
        #pragma unroll
        for (int kt = 0; kt < 2; ++kt) {
            f16x8 f;
            #pragma unroll
            for (int jj = 0; jj < 8; ++jj) {
                int u = 32 * kt + 8 * g + jj;
                f[jj] = (f16)((ook && u < UNITD) ? wr[u] : 0.f);
            }
            wf[512 + (mo * 2 + kt) * 64 + lane] = f;
        }
    }
    // RoPE table (0.25 QK-scale baked as 0.5 per side); sgn=+1 d odd, -1 d even
    {
        float2* rt = (float2*)(ws + WS_ROPE);
        int seq = threadIdx.x;     // 0..63
        #pragma unroll
        for (int d = 0; d < 16; ++d) {
            float ang = (float)seq * expf(-(float)(d >> 1) * 1.1512925464970229f);
            float sn, cs;
            sincosf(ang, &sn, &cs);
            float2 v; v.x = cs * 0.5f; v.y = ((d & 1) ? sn : -sn) * 0.5f;
            rt[seq * 16 + d] = v;
        }
    }
    // wv[u] = sum_o Wo[o][u]*Wq[o] (zero-padded to 64); c0 = bo·Wq + bq
    {
        float* wv = (float*)(ws + WS_WV);
        int u = threadIdx.x;
        float s = 0.f;
        if (u < UNITD)
            for (int o = 0; o < UNITD; ++o) s += Wo[(size_t)o * UNITD + u] * Wq[o];
        wv[u] = s;
    }
    if (threadIdx.x == 0) {
        float s = bq[0];
        for (int o = 0; o < UNITD; ++o) s += bo[o] * Wq[o];
        *(float*)(ws + WS_C0) = s;
    }
}

__global__ __launch_bounds__(256, 3) void gau_kernel(
    const float* __restrict__ x,
    const float* __restrict__ mask,
    const char* __restrict__ ws,
    const float* __restrict__ bi,
    const float* __restrict__ bo,
    const float* __restrict__ sq,
    const float* __restrict__ oq,
    const float* __restrict__ sk,
    const float* __restrict__ ok,
    float* __restrict__ out,
    int Btot)
{
    const int lane = threadIdx.x & 63;
    const int wid  = threadIdx.x >> 6;
    const int b    = blockIdx.x * 4 + wid;
    const int g    = lane >> 4;
    const int t    = lane & 15;

    const f16x8* wf = (const f16x8*)ws;

    __shared__ __align__(16) char smem[4 * ARENA];
    char* wa = smem + wid * ARENA;
    float* M = (float*)(wa + MOFF);

    if (b >= Btot) return;

    M[lane] = (lane < SEQ) ? mask[(size_t)b * SEQ + lane] : 0.f;

    // ================= phase B: h = silu(x @ Wi[46:108]^T + bi) =================
    f16x8 bfW[4][2];
    float biv[4];
    #pragma unroll
    for (int nt = 0; nt < 4; ++nt) {
        int c = t + 16 * nt;
        biv[nt] = (c < 62) ? bi[UNITD + c] : 0.f;
        #pragma unroll
        for (int kt = 0; kt < 2; ++kt)
            bfW[nt][kt] = wf[(nt * 2 + kt) * 64 + lane];
    }

    f32x4 hB[4][4];
    #pragma unroll
    for (int mt = 0; mt < 4; ++mt)
        #pragma unroll
        for (int nt = 0; nt < 4; ++nt) {
            f32x4 c; c[0] = biv[nt]; c[1] = biv[nt]; c[2] = biv[nt]; c[3] = biv[nt];
            hB[mt][nt] = c;
        }

    const float* xb = x + (size_t)b * (SEQ * UNITD);
    #pragma unroll
    for (int mt = 0; mt < 4; ++mt) {
        int row = 16 * mt + t; if (row > SEQ - 1) row = SEQ - 1;
        const float* xr = xb + row * UNITD;
        #pragma unroll
        for (int kt = 0; kt < 2; ++kt) {
            u32x4 axw;
            #pragma unroll
            for (int jj2 = 0; jj2 < 4; ++jj2) {
                int u = 32 * kt + 8 * g + 2 * jj2;
                float lo = 0.f, hi = 0.f;
                if (u < UNITD) { float2 w = *(const float2*)(xr + u); lo = w.x; hi = w.y; }
                axw[jj2] = pk2(lo, hi);
            }
            f16x8 ax = __builtin_bit_cast(f16x8, axw);
            #pragma unroll
            for (int nt = 0; nt < 4; ++nt)
                hB[mt][nt] = __builtin_amdgcn_mfma_f32_16x16x32_f16(ax, bfW[nt][kt], hB[mt][nt], 0, 0, 0);
        }
    }

    // ---- silu; v -> V^T LDS (f16); qk channels kept in regs ----
    float qkv[4][4];
    #pragma unroll
    for (int mt = 0; mt < 4; ++mt) {
        float s2[4], s3[4];
        #pragma unroll
        for (int nt = 0; nt < 4; ++nt) {
            float sl[4];
            #pragma unroll
            for (int r = 0; r < 4; ++r) {
                float h = hB[mt][nt][r];
                sl[r] = h * rcpf(1.f + __expf(-h));
            }
            int ucol = t + 16 * nt;
            if (nt < 3 && ucol < UNITD) {
                u32x2 pw; pw[0] = pk2(sl[0], sl[1]); pw[1] = pk2(sl[2], sl[3]);
                *(f16x4*)(wa + swzV(ucol, (16 * mt + 4 * g) * 2)) = __builtin_bit_cast(f16x4, pw);
            }
            if (nt == 2) { s2[0]=sl[0]; s2[1]=sl[1]; s2[2]=sl[2]; s2[3]=sl[3]; }
            if (nt == 3) { s3[0]=sl[0]; s3[1]=sl[1]; s3[2]=sl[2]; s3[3]=sl[3]; }
        }
        #pragma unroll
        for (int r = 0; r < 4; ++r) qkv[mt][r] = (t >= 14) ? s2[r] : s3[r];
    }

    // ================= phase C: RoPE via table; q,k -> LDS (overlaying P region) =================
    {
        f16* Q = (f16*)(wa + QOFF);
        f16* K = (f16*)(wa + KOFF);
        const float2* rt = (const float2*)(ws + WS_ROPE);
        int d = (t >= 14) ? (t - 14) : (t + 2);
        float sqd = sq[d], oqd = oq[d], skd = sk[d], okd = ok[d];
        #pragma unroll
        for (int mt = 0; mt < 4; ++mt)
            #pragma unroll
            for (int r = 0; r < 4; ++r) {
                int seq = 16 * mt + 4 * g + r;
                float2 cn = rt[seq * 16 + d];     // (cos*0.5, sgn*sin*0.5)
                float qv = qkv[mt][r] * sqd + oqd;
                float kv = qkv[mt][r] * skd + okd;
                float qp = dmov<0xB1>(qv);        // partner (lane^1) via DPP
                float kp = dmov<0xB1>(kv);
                Q[seq * 20 + d] = (f16)(qv * cn.x + qp * cn.y);
                K[seq * 20 + d] = (f16)(kv * cn.x + kp * cn.y);
            }
    }

    // ================= phase D: P^T = q'k'^T (0.25 baked), masked, softmax =================
    f16x4 ak[4], bq_[4];
    #pragma unroll
    for (int m4 = 0; m4 < 4; ++m4) ak[m4]  = *(f16x4*)(wa + KOFF + (16 * m4 + t) * 40 + 8 * g);
    #pragma unroll
    for (int n4 = 0; n4 < 4; ++n4) bq_[n4] = *(f16x4*)(wa + QOFF + (16 * n4 + t) * 40 + 8 * g);

    f32x4 pT[4][4];
    #pragma unroll
    for (int m4 = 0; m4 < 4; ++m4)
        #pragma unroll
        for (int n4 = 0; n4 < 4; ++n4) {
            f32x4 z; z[0]=0.f; z[1]=0.f; z[2]=0.f; z[3]=0.f;
            pT[m4][n4] = __builtin_amdgcn_mfma_f32_16x16x16f16(ak[m4], bq_[n4], z, 0, 0, 0);
        }

    f32x4 mj4[4];
    float NBv[4][4];
    #pragma unroll
    for (int m4 = 0; m4 < 4; ++m4) {
        mj4[m4] = *(f32x4*)(M + 16 * m4 + 4 * g);
        #pragma unroll
        for (int r = 0; r < 4; ++r)
            NBv[m4][r] = fmaf(mj4[m4][r], NEGBIG, -NEGBIG);    // (m-1)*BIG
    }

    // Q/K region is dead once pT is computed; P writes below overwrite it.
    #pragma unroll
    for (int n4 = 0; n4 < 4; ++n4) {
        float a_[4][4];
        #pragma unroll
        for (int m4 = 0; m4 < 4; ++m4)
            #pragma unroll
            for (int r = 0; r < 4; ++r)
                a_[m4][r] = fmaf(pT[m4][n4][r], mj4[m4][r], NBv[m4][r]);

        float mr[4];
        #pragma unroll
        for (int m4 = 0; m4 < 4; ++m4)
            mr[m4] = fmaxf(fmaxf(a_[m4][0], a_[m4][1]), fmaxf(a_[m4][2], a_[m4][3]));
        float mx = fmaxf(fmaxf(mr[0], mr[1]), fmaxf(mr[2], mr[3]));
        mx = fmaxf(mx, __shfl_xor(mx, 16)); mx = fmaxf(mx, __shfl_xor(mx, 32));

        float sr[4];
        #pragma unroll
        for (int m4 = 0; m4 < 4; ++m4) {
            #pragma unroll
            for (int r = 0; r < 4; ++r) a_[m4][r] = __expf(a_[m4][r] - mx);
            sr[m4] = (a_[m4][0] + a_[m4][1]) + (a_[m4][2] + a_[m4][3]);
        }
        float sm = (sr[0] + sr[1]) + (sr[2] + sr[3]);
        sm += __shfl_xor(sm, 16); sm += __shfl_xor(sm, 32);
        float inv = rcpf(sm);

        int i = t + 16 * n4;
        if (i < SEQ) {
            #pragma unroll
            for (int m4 = 0; m4 < 4; ++m4) {
                u32x2 pw;
                pw[0] = pk2(a_[m4][0] * inv, a_[m4][1] * inv);
                pw[1] = pk2(a_[m4][2] * inv, a_[m4][3] * inv);
                *(f16x4*)(wa + swzP(i, (16 * m4 + 4 * g) * 2)) = __builtin_bit_cast(f16x4, pw);
            }
        }
    }

    // ================= phase F: out = P @ v =================
    f16x8 bv[3][2];
    #pragma unroll
    for (int nt = 0; nt < 3; ++nt) {
        int vr = t + 16 * nt; if (vr > UNITD - 1) vr = UNITD - 1;   // clamp: avoid uninit LDS (finite garbage, killed by wv=0)
        #pragma unroll
        for (int kt = 0; kt < 2; ++kt)
            bv[nt][kt] = *(f16x8*)(wa + swzV(vr, (32 * kt + 8 * g) * 2));
    }

    f32x4 oA[4][3];
    #pragma unroll
    for (int mt = 0; mt < 4; ++mt)
        #pragma unroll
        for (int nt = 0; nt < 3; ++nt) { f32x4 z; z[0]=0.f; z[1]=0.f; z[2]=0.f; z[3]=0.f; oA[mt][nt] = z; }

    #pragma unroll
    for (int mt = 0; mt < 4; ++mt) {
        int pr = 16 * mt + t; if (pr > SEQ - 1) pr = SEQ - 1;
        #pragma unroll
        for (int kt = 0; kt < 2; ++kt) {
            f16x8 ap = *(f16x8*)(wa + swzP(pr, (32 * kt + 8 * g) * 2));
            #pragma unroll
            for (int nt = 0; nt < 3; ++nt)
                oA[mt][nt] = __builtin_amdgcn_mfma_f32_16x16x32_f16(ap, bv[nt][kt], oA[mt][nt], 0, 0, 0);
        }
    }

    // ================= tail: hq = out·wv ; prob softmax ; z = Σ prob·out ; out = Wo@z+bo =====
    // oA layout: element r ↔ row i = 16mt+4g+r, col u = t+16nt
    const float* wvp = (const float*)(ws + WS_WV);
    const float c0 = *(const float*)(ws + WS_C0);
    float wvv0 = wvp[t], wvv1 = wvp[t + 16], wvv2 = wvp[t + 32];   // wv[u>=46]=0

    float hq[4][4];
    #pragma unroll
    for (int mt = 0; mt < 4; ++mt)
        #pragma unroll
        for (int r = 0; r < 4; ++r) {
            float s = oA[mt][0][r] * wvv0;
            s = fmaf(oA[mt][1][r], wvv1, s);
            s = fmaf(oA[mt][2][r], wvv2, s);
            hq[mt][r] = dsum16(s);                 // reduce over t (u-partials)
        }

    // masked logits; i>=50 killed by M=0 -> -BIG
    float tvv[4][4]; float mx2 = -INFINITY;
    #pragma unroll
    for (int mt = 0; mt < 4; ++mt)
        #pragma unroll
        for (int r = 0; r < 4; ++r) {
            float nbh = fmaf(c0, mj4[mt][r], NBv[mt][r]);
            float tv = fmaf(hq[mt][r], mj4[mt][r], nbh);
            tvv[mt][r] = tv;
            mx2 = fmaxf(mx2, tv);
        }
    mx2 = fmaxf(mx2, __shfl_xor(mx2, 16)); mx2 = fmaxf(mx2, __shfl_xor(mx2, 32));
    float sm2 = 0.f;
    #pragma unroll
    for (int mt = 0; mt < 4; ++mt)
        #pragma unroll
        for (int r = 0; r < 4; ++r) {
            float e = __expf(tvv[mt][r] - mx2);
            tvv[mt][r] = e; sm2 += e;
        }
    sm2 += __shfl_xor(sm2, 16); sm2 += __shfl_xor(sm2, 32);
    float inv2 = rcpf(sm2);

    // z[u] = sum_i prob_i * out[i][u]; per-lane partial over its 16 i values, then g-reduce
    float zp0 = 0.f, zp1 = 0.f, zp2 = 0.f;
    #pragma unroll
    for (int mt = 0; mt < 4; ++mt)
        #pragma unroll
        for (int r = 0; r < 4; ++r) {
            float p = tvv[mt][r];
            zp0 = fmaf(p, oA[mt][0][r], zp0);
            zp1 = fmaf(p, oA[mt][1][r], zp1);
            zp2 = fmaf(p, oA[mt][2][r], zp2);
        }
    zp0 += __shfl_xor(zp0, 16); zp0 += __shfl_xor(zp0, 32);
    zp1 += __shfl_xor(zp1, 16); zp1 += __shfl_xor(zp1, 32);
    zp2 += __shfl_xor(zp2, 16); zp2 += __shfl_xor(zp2, 32);
    zp0 *= inv2; zp1 *= inv2;
    zp2 = (t < 14) ? zp2 * inv2 : 0.f;                 // u>=46 -> 0 (avoid inf into f16)

    // z -> LDS f16 (P region dead), zero-pad to 64
    if (lane < 16) {
        *(f16*)(wa + 2 * t)        = (f16)zp0;
        *(f16*)(wa + 2 * (t + 16)) = (f16)zp1;
        *(f16*)(wa + 2 * (t + 32)) = (f16)zp2;
        *(f16*)(wa + 2 * (t + 48)) = (f16)0.f;
    }

    // result = Wo @ z + bo via 6 MFMAs (B = z broadcast over n)
    f16x8 bz0 = *(f16x8*)(wa + 16 * g);
    f16x8 bz1 = *(f16x8*)(wa + 64 + 16 * g);
    #pragma unroll
    for (int mo = 0; mo < 3; ++mo) {
        f32x4 res; res[0]=0.f; res[1]=0.f; res[2]=0.f; res[3]=0.f;
        res = __builtin_amdgcn_mfma_f32_16x16x32_f16(wf[512 + (mo * 2 + 0) * 64 + lane], bz0, res, 0, 0, 0);
        res = __builtin_amdgcn_mfma_f32_16x16x32_f16(wf[512 + (mo * 2 + 1) * 64 + lane], bz1, res, 0, 0, 0);
        if (t == 0) {
            #pragma unroll
            for (int r = 0; r < 4; ++r) {
                int o = 16 * mo + 4 * g + r;
                if (o < UNITD) out[(size_t)b * UNITD + o] = res[r] + bo[o];
            }
        }
    }
}

extern "C" void kernel_launch(void* const* d_in, const int* in_sizes, int n_in,
                              void* d_out, int out_size, void* d_ws, size_t ws_size,
                              hipStream_t stream) {
    const float* x    = (const float*)d_in[0];
    const float* mask = (const float*)d_in[1];
    const float* Wi   = (const float*)d_in[2];
    const float* bi   = (const float*)d_in[3];
    const float* Wo   = (const float*)d_in[4];
    const float* bo   = (const float*)d_in[5];
    const float* sq   = (const float*)d_in[6];
    const float* oq   = (const float*)d_in[7];
    const float* sk   = (const float*)d_in[8];
    const float* ok   = (const float*)d_in[9];
    const float* Wq   = (const float*)d_in[10];
    const float* bq   = (const float*)d_in[11];
    float* outp       = (float*)d_out;

    prep_kernel<<<1, 64, 0, stream>>>(Wi, Wo, Wq, bo, bq, (char*)d_ws);

    const int B = in_sizes[0] / (SEQ * UNITD);
    const int blocks = (B + 3) / 4;
    gau_kernel<<<blocks, 256, 0, stream>>>(x, mask, (const char*)d_ws, bi, bo,
                                           sq, oq, sk, ok, outp, B);
}

// Round 15
// 168.511 us; speedup vs baseline: 1.1041x; 1.1041x over previous
//
#include <hip/hip_runtime.h>
#include <math.h>

#define SEQ 50
#define UNITD 46
#define NEGBIG 1000000000000.0f

typedef _Float16 f16;
typedef f16 f16x4 __attribute__((ext_vector_type(4)));
typedef f16 f16x8 __attribute__((ext_vector_type(8)));
typedef float f32x4 __attribute__((ext_vector_type(4)));
typedef unsigned u32x2 __attribute__((ext_vector_type(2)));
typedef unsigned u32x4 __attribute__((ext_vector_type(4)));

__device__ __forceinline__ float rcpf(float x) { return __builtin_amdgcn_rcpf(x); }
__device__ __forceinline__ unsigned pk2(float lo, float hi) {
    return __builtin_bit_cast(unsigned, __builtin_amdgcn_cvt_pkrtz(lo, hi));
}

// ---- DPP cross-lane moves (VALU pipe, no DS-pipe cost) ----
template<int CTRL>
__device__ __forceinline__ float dmov(float x) {
    int v = __builtin_bit_cast(int, x);
    return __builtin_bit_cast(float, __builtin_amdgcn_update_dpp(v, v, CTRL, 0xF, 0xF, true));
}
__device__ __forceinline__ float dsum16(float x) {
    x += dmov<0xB1>(x);  x += dmov<0x4E>(x);
    x += dmov<0x141>(x); x += dmov<0x140>(x);
    return x;
}
__device__ __forceinline__ float dmax16(float x) {
    x = fmaxf(x, dmov<0xB1>(x));  x = fmaxf(x, dmov<0x4E>(x));
    x = fmaxf(x, dmov<0x141>(x)); x = fmaxf(x, dmov<0x140>(x));
    return x;
}

// ---- per-wave arena (bytes) ----
// [0,2560)      Q [64 rows][20 halves]
// [2560,5120)   K [64 rows][20 halves]
// [6400,12544)  V^T [48][128B] swizzled (row=u, col=seq)
// [12544,12800) M [64] f32 (mask, zero-padded)
#define ARENA 12800
#define QOFF 0
#define KOFF 2560
#define VOFF 6400
#define MOFF 12544

__device__ __forceinline__ int swzV(int row, int colbyte) {
    return VOFF + row * 128 + (colbyte ^ ((row & 7) << 4));
}

// ---- ws layout ----
// [0,8192):      Wi B-frags f16x8[512] (K=32 layout)
// [8192,12800):  Wo A-frags u32x2[576] (K=16 layout: A[m=o=16mo+t][k=u=16kt2+4g+jj])
// [14336,22528): rope table float2[64*16] = (cos*0.5, sgn*sin*0.5)
#define WS_WO   8192
#define WS_ROPE 14336

__global__ void prep_kernel(const float* __restrict__ Wi,
                            const float* __restrict__ Wo,
                            char* __restrict__ ws)
{
    f16x8* wf = (f16x8*)ws;
    u32x2* wo2 = (u32x2*)(ws + WS_WO);
    const int lane = threadIdx.x & 63;
    const int g = lane >> 4, t = lane & 15;
    // Wi B-frags (K=32): B[k=u][n=c], n=t+16nt, k=32kt+8g+jj
    #pragma unroll
    for (int nt = 0; nt < 4; ++nt) {
        int c = t + 16 * nt; bool cok = c < 62;
        const float* wr = Wi + (size_t)(UNITD + (cok ? c : 0)) * UNITD;
        #pragma unroll
        for (int kt = 0; kt < 2; ++kt) {
            f16x8 f;
            #pragma unroll
            for (int jj = 0; jj < 8; ++jj) {
                int u = 32 * kt + 8 * g + jj;
                f[jj] = (f16)((cok && u < UNITD) ? wr[u] : 0.f);
            }
            wf[(nt * 2 + kt) * 64 + lane] = f;
        }
    }
    // Wo A-frags (K=16): A[m=o][k=u], o=16mo+t, u=16kt2+4g+jj
    #pragma unroll
    for (int mo = 0; mo < 3; ++mo) {
        int o = 16 * mo + t; bool ook = o < UNITD;
        const float* wr = Wo + (size_t)(ook ? o : 0) * UNITD;
        #pragma unroll
        for (int kt2 = 0; kt2 < 3; ++kt2) {
            float v[4];
            #pragma unroll
            for (int jj = 0; jj < 4; ++jj) {
                int u = 16 * kt2 + 4 * g + jj;
                v[jj] = (ook && u < UNITD) ? wr[u] : 0.f;
            }
            u32x2 f; f[0] = pk2(v[0], v[1]); f[1] = pk2(v[2], v[3]);
            wo2[(mo * 3 + kt2) * 64 + lane] = f;
        }
    }
    // RoPE table (0.25 QK-scale baked as 0.5 per side); sgn=+1 d odd, -1 d even
    {
        float2* rt = (float2*)(ws + WS_ROPE);
        int seq = threadIdx.x;     // 0..63
        #pragma unroll
        for (int d = 0; d < 16; ++d) {
            float ang = (float)seq * expf(-(float)(d >> 1) * 1.1512925464970229f);
            float sn, cs;
            sincosf(ang, &sn, &cs);
            float2 v; v.x = cs * 0.5f; v.y = ((d & 1) ? sn : -sn) * 0.5f;
            rt[seq * 16 + d] = v;
        }
    }
}

__global__ __launch_bounds__(256, 3) void gau_kernel(
    const float* __restrict__ x,
    const float* __restrict__ mask,
    const char* __restrict__ ws,
    const float* __restrict__ bi,
    const float* __restrict__ bo,
    const float* __restrict__ sq,
    const float* __restrict__ oq,
    const float* __restrict__ sk,
    const float* __restrict__ ok,
    const float* __restrict__ Wq,
    const float* __restrict__ bq,
    float* __restrict__ out,
    int Btot)
{
    const int lane = threadIdx.x & 63;
    const int wid  = threadIdx.x >> 6;
    const int b    = blockIdx.x * 4 + wid;
    const int g    = lane >> 4;
    const int t    = lane & 15;

    const f16x8* wf = (const f16x8*)ws;
    const u32x2* wo2 = (const u32x2*)(ws + WS_WO);

    __shared__ __align__(16) char smem[4 * ARENA];
    char* wa = smem + wid * ARENA;
    float* M = (float*)(wa + MOFF);

    if (b >= Btot) return;

    M[lane] = (lane < SEQ) ? mask[(size_t)b * SEQ + lane] : 0.f;

    // ================= phase B: h = silu(x @ Wi[46:108]^T + bi) =================
    f16x8 bfW[4][2];
    float biv[4];
    #pragma unroll
    for (int nt = 0; nt < 4; ++nt) {
        int c = t + 16 * nt;
        biv[nt] = (c < 62) ? bi[UNITD + c] : 0.f;
        #pragma unroll
        for (int kt = 0; kt < 2; ++kt)
            bfW[nt][kt] = wf[(nt * 2 + kt) * 64 + lane];
    }

    f32x4 hB[4][4];
    #pragma unroll
    for (int mt = 0; mt < 4; ++mt)
        #pragma unroll
        for (int nt = 0; nt < 4; ++nt) {
            f32x4 c; c[0] = biv[nt]; c[1] = biv[nt]; c[2] = biv[nt]; c[3] = biv[nt];
            hB[mt][nt] = c;
        }

    const float* xb = x + (size_t)b * (SEQ * UNITD);
    #pragma unroll
    for (int mt = 0; mt < 4; ++mt) {
        int row = 16 * mt + t; if (row > SEQ - 1) row = SEQ - 1;
        const float* xr = xb + row * UNITD;
        #pragma unroll
        for (int kt = 0; kt < 2; ++kt) {
            u32x4 axw;
            #pragma unroll
            for (int jj2 = 0; jj2 < 4; ++jj2) {
                int u = 32 * kt + 8 * g + 2 * jj2;
                float lo = 0.f, hi = 0.f;
                if (u < UNITD) { float2 w = *(const float2*)(xr + u); lo = w.x; hi = w.y; }
                axw[jj2] = pk2(lo, hi);
            }
            f16x8 ax = __builtin_bit_cast(f16x8, axw);
            #pragma unroll
            for (int nt = 0; nt < 4; ++nt)
                hB[mt][nt] = __builtin_amdgcn_mfma_f32_16x16x32_f16(ax, bfW[nt][kt], hB[mt][nt], 0, 0, 0);
        }
    }

    // ---- silu; v -> V^T LDS (f16); qk channels kept in regs ----
    float qkv[4][4];
    #pragma unroll
    for (int mt = 0; mt < 4; ++mt) {
        float s2[4], s3[4];
        #pragma unroll
        for (int nt = 0; nt < 4; ++nt) {
            float sl[4];
            #pragma unroll
            for (int r = 0; r < 4; ++r) {
                float h = hB[mt][nt][r];
                sl[r] = h * rcpf(1.f + __expf(-h));
            }
            int ucol = t + 16 * nt;
            if (nt < 3 && ucol < UNITD) {
                u32x2 pw; pw[0] = pk2(sl[0], sl[1]); pw[1] = pk2(sl[2], sl[3]);
                *(f16x4*)(wa + swzV(ucol, (16 * mt + 4 * g) * 2)) = __builtin_bit_cast(f16x4, pw);
            }
            if (nt == 2) { s2[0]=sl[0]; s2[1]=sl[1]; s2[2]=sl[2]; s2[3]=sl[3]; }
            if (nt == 3) { s3[0]=sl[0]; s3[1]=sl[1]; s3[2]=sl[2]; s3[3]=sl[3]; }
        }
        #pragma unroll
        for (int r = 0; r < 4; ++r) qkv[mt][r] = (t >= 14) ? s2[r] : s3[r];
    }

    // ================= phase C: RoPE via table; q,k -> LDS =================
    {
        f16* Q = (f16*)(wa + QOFF);
        f16* K = (f16*)(wa + KOFF);
        const float2* rt = (const float2*)(ws + WS_ROPE);
        int d = (t >= 14) ? (t - 14) : (t + 2);
        float sqd = sq[d], oqd = oq[d], skd = sk[d], okd = ok[d];
        #pragma unroll
        for (int mt = 0; mt < 4; ++mt)
            #pragma unroll
            for (int r = 0; r < 4; ++r) {
                int seq = 16 * mt + 4 * g + r;
                float2 cn = rt[seq * 16 + d];     // (cos*0.5, sgn*sin*0.5)
                float qv = qkv[mt][r] * sqd + oqd;
                float kv = qkv[mt][r] * skd + okd;
                float qp = dmov<0xB1>(qv);        // partner (lane^1) via DPP
                float kp = dmov<0xB1>(kv);
                Q[seq * 20 + d] = (f16)(qv * cn.x + qp * cn.y);
                K[seq * 20 + d] = (f16)(kv * cn.x + kp * cn.y);
            }
    }

    // ================= phase D: P^T = q'k'^T (0.25 baked), masked, softmax (in-register) =====
    f16x4 ak[4], bq_[4];
    #pragma unroll
    for (int m4 = 0; m4 < 4; ++m4) ak[m4]  = *(f16x4*)(wa + KOFF + (16 * m4 + t) * 40 + 8 * g);
    #pragma unroll
    for (int n4 = 0; n4 < 4; ++n4) bq_[n4] = *(f16x4*)(wa + QOFF + (16 * n4 + t) * 40 + 8 * g);

    f32x4 pT[4][4];
    #pragma unroll
    for (int m4 = 0; m4 < 4; ++m4)
        #pragma unroll
        for (int n4 = 0; n4 < 4; ++n4) {
            f32x4 z; z[0]=0.f; z[1]=0.f; z[2]=0.f; z[3]=0.f;
            pT[m4][n4] = __builtin_amdgcn_mfma_f32_16x16x16f16(ak[m4], bq_[n4], z, 0, 0, 0);
        }

    f32x4 mj4[4];
    float NBv[4][4];
    #pragma unroll
    for (int m4 = 0; m4 < 4; ++m4) {
        mj4[m4] = *(f32x4*)(M + 16 * m4 + 4 * g);
        #pragma unroll
        for (int r = 0; r < 4; ++r)
            NBv[m4][r] = fmaf(mj4[m4][r], NEGBIG, -NEGBIG);    // (m-1)*BIG
    }

    // P stays in registers as PV's B-fragments: pb[n4][m4] holds P^T[j=16m4+4g+jj][i=16n4+t]
    f16x4 pb[4][4];
    #pragma unroll
    for (int n4 = 0; n4 < 4; ++n4) {
        float a_[4][4];
        #pragma unroll
        for (int m4 = 0; m4 < 4; ++m4)
            #pragma unroll
            for (int r = 0; r < 4; ++r)
                a_[m4][r] = fmaf(pT[m4][n4][r], mj4[m4][r], NBv[m4][r]);

        float mr[4];
        #pragma unroll
        for (int m4 = 0; m4 < 4; ++m4)
            mr[m4] = fmaxf(fmaxf(a_[m4][0], a_[m4][1]), fmaxf(a_[m4][2], a_[m4][3]));
        float mx = fmaxf(fmaxf(mr[0], mr[1]), fmaxf(mr[2], mr[3]));
        mx = fmaxf(mx, __shfl_xor(mx, 16)); mx = fmaxf(mx, __shfl_xor(mx, 32));

        float sr[4];
        #pragma unroll
        for (int m4 = 0; m4 < 4; ++m4) {
            #pragma unroll
            for (int r = 0; r < 4; ++r) a_[m4][r] = __expf(a_[m4][r] - mx);
            sr[m4] = (a_[m4][0] + a_[m4][1]) + (a_[m4][2] + a_[m4][3]);
        }
        float sm = (sr[0] + sr[1]) + (sr[2] + sr[3]);
        sm += __shfl_xor(sm, 16); sm += __shfl_xor(sm, 32);
        float inv = rcpf(sm);

        #pragma unroll
        for (int m4 = 0; m4 < 4; ++m4) {
            u32x2 pw;
            pw[0] = pk2(a_[m4][0] * inv, a_[m4][1] * inv);
            pw[1] = pk2(a_[m4][2] * inv, a_[m4][3] * inv);
            pb[n4][m4] = __builtin_bit_cast(f16x4, pw);
        }
    }

    // ================= phase F: out^T = V^T @ P^T  (A from LDS, B from regs) =============
    // oT[nt][n4]: C[m=u=16nt+4g+r][n=i=16n4+t]
    f32x4 oT[3][4];
    #pragma unroll
    for (int nt = 0; nt < 3; ++nt)
        #pragma unroll
        for (int n4 = 0; n4 < 4; ++n4) { f32x4 z; z[0]=0.f; z[1]=0.f; z[2]=0.f; z[3]=0.f; oT[nt][n4] = z; }

    #pragma unroll
    for (int nt = 0; nt < 3; ++nt) {
        int vr = t + 16 * nt; if (vr > UNITD - 1) vr = UNITD - 1;   // clamp: rows 46,47 uninit; u>=46 killed by Wo frag zeros
        #pragma unroll
        for (int m4 = 0; m4 < 4; ++m4) {
            f16x4 av = *(f16x4*)(wa + swzV(vr, (16 * m4 + 4 * g) * 2));
            #pragma unroll
            for (int n4 = 0; n4 < 4; ++n4)
                oT[nt][n4] = __builtin_amdgcn_mfma_f32_16x16x16f16(av, pb[n4][m4], oT[nt][n4], 0, 0, 0);
        }
    }

    // ================= phase G: out2^T = Wo @ out^T (+bo as C-init), all in-register ======
    float bov[3][4], wqv[3][4];
    #pragma unroll
    for (int mo = 0; mo < 3; ++mo)
        #pragma unroll
        for (int r = 0; r < 4; ++r) {
            int o = 16 * mo + 4 * g + r; bool ok2 = (o < UNITD);
            bov[mo][r] = ok2 ? bo[o] : 0.f;
            wqv[mo][r] = ok2 ? Wq[o] : 0.f;
        }

    f32x4 o2[3][4];
    #pragma unroll
    for (int mo = 0; mo < 3; ++mo)
        #pragma unroll
        for (int n4 = 0; n4 < 4; ++n4) {
            f32x4 c;
            #pragma unroll
            for (int r = 0; r < 4; ++r) c[r] = bov[mo][r];
            o2[mo][n4] = c;
        }

    #pragma unroll
    for (int kt2 = 0; kt2 < 3; ++kt2) {
        f16x4 awf[3];
        #pragma unroll
        for (int mo = 0; mo < 3; ++mo)
            awf[mo] = __builtin_bit_cast(f16x4, wo2[(mo * 3 + kt2) * 64 + lane]);
        #pragma unroll
        for (int n4 = 0; n4 < 4; ++n4) {
            u32x2 bw;
            bw[0] = pk2(oT[kt2][n4][0], oT[kt2][n4][1]);
            bw[1] = pk2(oT[kt2][n4][2], oT[kt2][n4][3]);
            f16x4 bof = __builtin_bit_cast(f16x4, bw);
            #pragma unroll
            for (int mo = 0; mo < 3; ++mo)
                o2[mo][n4] = __builtin_amdgcn_mfma_f32_16x16x16f16(awf[mo], bof, o2[mo][n4], 0, 0, 0);
        }
    }

    // ================= phase H: prob = softmax_i(out2 . Wq + bq, masked) =================
    float bq0 = bq[0];
    float tv[4]; float mx2 = -INFINITY;
    #pragma unroll
    for (int n4 = 0; n4 < 4; ++n4) {
        float s = 0.f;
        #pragma unroll
        for (int mo = 0; mo < 3; ++mo)
            #pragma unroll
            for (int r = 0; r < 4; ++r) s += o2[mo][n4][r] * wqv[mo][r];
        s += __shfl_xor(s, 16); s += __shfl_xor(s, 32);
        float mi = M[t + 16 * n4];
        float nb = fmaf(mi, NEGBIG, -NEGBIG);
        tv[n4] = fmaf(s + bq0, mi, nb);
        mx2 = fmaxf(mx2, tv[n4]);
    }
    mx2 = dmax16(mx2);
    float sm2 = 0.f;
    #pragma unroll
    for (int n4 = 0; n4 < 4; ++n4) { float e = __expf(tv[n4] - mx2); tv[n4] = e; sm2 += e; }
    sm2 = dsum16(sm2);
    float inv2 = rcpf(sm2);

    // ================= phase I: result[o] = sum_i out2[i][o] * prob[i] =================
    #pragma unroll
    for (int mo = 0; mo < 3; ++mo) {
        float racc[4];
        #pragma unroll
        for (int r = 0; r < 4; ++r) {
            float a = 0.f;
            #pragma unroll
            for (int n4 = 0; n4 < 4; ++n4) a += o2[mo][n4][r] * tv[n4];
            racc[r] = dsum16(a);
        }
        if (t == 0) {
            #pragma unroll
            for (int r = 0; r < 4; ++r) {
                int o = 16 * mo + 4 * g + r;
                if (o < UNITD) out[(size_t)b * UNITD + o] = racc[r] * inv2;
            }
        }
    }
}

extern "C" void kernel_launch(void* const* d_in, const int* in_sizes, int n_in,
                              void* d_out, int out_size, void* d_ws, size_t ws_size,
                              hipStream_t stream) {
    const float* x    = (const float*)d_in[0];
    const float* mask = (const float*)d_in[1];
    const float* Wi   = (const float*)d_in[2];
    const float* bi   = (const float*)d_in[3];
    const float* Wo   = (const float*)d_in[4];
    const float* bo   = (const float*)d_in[5];
    const float* sq   = (const float*)d_in[6];
    const float* oq   = (const float*)d_in[7];
    const float* sk   = (const float*)d_in[8];
    const float* ok   = (const float*)d_in[9];
    const float* Wq   = (const float*)d_in[10];
    const float* bq   = (const float*)d_in[11];
    float* outp       = (float*)d_out;

    prep_kernel<<<1, 64, 0, stream>>>(Wi, Wo, (char*)d_ws);

    const int B = in_sizes[0] / (SEQ * UNITD);
    const int blocks = (B + 3) / 4;
    gau_kernel<<<blocks, 256, 0, stream>>>(x, mask, (const char*)d_ws, bi, bo,
                                           sq, oq, sk, ok, Wq, bq, outp, B);
}

// Round 16
// 167.200 us; speedup vs baseline: 1.1128x; 1.0078x over previous
//
#include <hip/hip_runtime.h>
#include <math.h>

#define SEQ 50
#define UNITD 46
#define NEGBIG 1000000000000.0f

typedef _Float16 f16;
typedef f16 f16x4 __attribute__((ext_vector_type(4)));
typedef f16 f16x8 __attribute__((ext_vector_type(8)));
typedef float f32x4 __attribute__((ext_vector_type(4)));
typedef unsigned u32x2 __attribute__((ext_vector_type(2)));
typedef unsigned u32x4 __attribute__((ext_vector_type(4)));

__device__ __forceinline__ float rcpf(float x) { return __builtin_amdgcn_rcpf(x); }
__device__ __forceinline__ unsigned pk2(float lo, float hi) {
    return __builtin_bit_cast(unsigned, __builtin_amdgcn_cvt_pkrtz(lo, hi));
}

// ---- DPP cross-lane moves (VALU pipe, no DS-pipe cost) ----
template<int CTRL>
__device__ __forceinline__ float dmov(float x) {
    int v = __builtin_bit_cast(int, x);
    return __builtin_bit_cast(float, __builtin_amdgcn_update_dpp(v, v, CTRL, 0xF, 0xF, true));
}
__device__ __forceinline__ float dsum16(float x) {
    x += dmov<0xB1>(x);  x += dmov<0x4E>(x);
    x += dmov<0x141>(x); x += dmov<0x140>(x);
    return x;
}
__device__ __forceinline__ float dmax16(float x) {
    x = fmaxf(x, dmov<0xB1>(x));  x = fmaxf(x, dmov<0x4E>(x));
    x = fmaxf(x, dmov<0x141>(x)); x = fmaxf(x, dmov<0x140>(x));
    return x;
}

// ---- per-wave arena (bytes), compacted to 10240 -> 4 blocks/CU ----
// [0,2000)      Q [50 rows][20 halves]
// [2000,4000)   K [50 rows][20 halves]
// [4000,9888)   V^T [46][128B] swizzled (row=u, col=seq)
// [9888,10144)  M [64] f32 (mask, zero-padded); [10144,10240) pad
#define ARENA 10240
#define QOFF 0
#define KOFF 2000
#define VOFF 4000
#define MOFF 9888

__device__ __forceinline__ int swzV(int row, int colbyte) {
    return VOFF + row * 128 + (colbyte ^ ((row & 7) << 4));
}

// ---- ws layout ----
// [0,8192):      Wi B-frags f16x8[512] (K=32 layout)
// [8192,12800):  Wo A-frags u32x2[576] (K=16 layout: A[m=o=16mo+t][k=u=16kt2+4g+jj])
// [14336,22528): rope table float2[64*16] = (cos*0.5, sgn*sin*0.5)
#define WS_WO   8192
#define WS_ROPE 14336

__global__ void prep_kernel(const float* __restrict__ Wi,
                            const float* __restrict__ Wo,
                            char* __restrict__ ws)
{
    f16x8* wf = (f16x8*)ws;
    u32x2* wo2 = (u32x2*)(ws + WS_WO);
    const int lane = threadIdx.x & 63;
    const int g = lane >> 4, t = lane & 15;
    // Wi B-frags (K=32): B[k=u][n=c], n=t+16nt, k=32kt+8g+jj
    #pragma unroll
    for (int nt = 0; nt < 4; ++nt) {
        int c = t + 16 * nt; bool cok = c < 62;
        const float* wr = Wi + (size_t)(UNITD + (cok ? c : 0)) * UNITD;
        #pragma unroll
        for (int kt = 0; kt < 2; ++kt) {
            f16x8 f;
            #pragma unroll
            for (int jj = 0; jj < 8; ++jj) {
                int u = 32 * kt + 8 * g + jj;
                f[jj] = (f16)((cok && u < UNITD) ? wr[u] : 0.f);
            }
            wf[(nt * 2 + kt) * 64 + lane] = f;
        }
    }
    // Wo A-frags (K=16): A[m=o][k=u], o=16mo+t, u=16kt2+4g+jj
    #pragma unroll
    for (int mo = 0; mo < 3; ++mo) {
        int o = 16 * mo + t; bool ook = o < UNITD;
        const float* wr = Wo + (size_t)(ook ? o : 0) * UNITD;
        #pragma unroll
        for (int kt2 = 0; kt2 < 3; ++kt2) {
            float v[4];
            #pragma unroll
            for (int jj = 0; jj < 4; ++jj) {
                int u = 16 * kt2 + 4 * g + jj;
                v[jj] = (ook && u < UNITD) ? wr[u] : 0.f;
            }
            u32x2 f; f[0] = pk2(v[0], v[1]); f[1] = pk2(v[2], v[3]);
            wo2[(mo * 3 + kt2) * 64 + lane] = f;
        }
    }
    // RoPE table (0.25 QK-scale baked as 0.5 per side); sgn=+1 d odd, -1 d even
    {
        float2* rt = (float2*)(ws + WS_ROPE);
        int seq = threadIdx.x;     // 0..63
        #pragma unroll
        for (int d = 0; d < 16; ++d) {
            float ang = (float)seq * expf(-(float)(d >> 1) * 1.1512925464970229f);
            float sn, cs;
            sincosf(ang, &sn, &cs);
            float2 v; v.x = cs * 0.5f; v.y = ((d & 1) ? sn : -sn) * 0.5f;
            rt[seq * 16 + d] = v;
        }
    }
}

__global__ __launch_bounds__(256, 4) void gau_kernel(
    const float* __restrict__ x,
    const float* __restrict__ mask,
    const char* __restrict__ ws,
    const float* __restrict__ bi,
    const float* __restrict__ bo,
    const float* __restrict__ sq,
    const float* __restrict__ oq,
    const float* __restrict__ sk,
    const float* __restrict__ ok,
    const float* __restrict__ Wq,
    const float* __restrict__ bq,
    float* __restrict__ out,
    int Btot)
{
    const int lane = threadIdx.x & 63;
    const int wid  = threadIdx.x >> 6;
    const int b    = blockIdx.x * 4 + wid;
    const int g    = lane >> 4;
    const int t    = lane & 15;

    const f16x8* wf = (const f16x8*)ws;
    const u32x2* wo2 = (const u32x2*)(ws + WS_WO);

    __shared__ __align__(16) char smem[4 * ARENA];
    char* wa = smem + wid * ARENA;
    float* M = (float*)(wa + MOFF);

    if (b >= Btot) return;

    M[lane] = (lane < SEQ) ? mask[(size_t)b * SEQ + lane] : 0.f;

    // ================= phase B: h = silu(x @ Wi[46:108]^T + bi) =================
    f16x8 bfW[4][2];
    float biv[4];
    #pragma unroll
    for (int nt = 0; nt < 4; ++nt) {
        int c = t + 16 * nt;
        biv[nt] = (c < 62) ? bi[UNITD + c] : 0.f;
        #pragma unroll
        for (int kt = 0; kt < 2; ++kt)
            bfW[nt][kt] = wf[(nt * 2 + kt) * 64 + lane];
    }

    f32x4 hB[4][4];
    #pragma unroll
    for (int mt = 0; mt < 4; ++mt)
        #pragma unroll
        for (int nt = 0; nt < 4; ++nt) {
            f32x4 c; c[0] = biv[nt]; c[1] = biv[nt]; c[2] = biv[nt]; c[3] = biv[nt];
            hB[mt][nt] = c;
        }

    const float* xb = x + (size_t)b * (SEQ * UNITD);
    #pragma unroll
    for (int mt = 0; mt < 4; ++mt) {
        int row = 16 * mt + t; if (row > SEQ - 1) row = SEQ - 1;
        const float* xr = xb + row * UNITD;
        #pragma unroll
        for (int kt = 0; kt < 2; ++kt) {
            u32x4 axw;
            #pragma unroll
            for (int jj2 = 0; jj2 < 4; ++jj2) {
                int u = 32 * kt + 8 * g + 2 * jj2;
                float lo = 0.f, hi = 0.f;
                if (u < UNITD) { float2 w = *(const float2*)(xr + u); lo = w.x; hi = w.y; }
                axw[jj2] = pk2(lo, hi);
            }
            f16x8 ax = __builtin_bit_cast(f16x8, axw);
            #pragma unroll
            for (int nt = 0; nt < 4; ++nt)
                hB[mt][nt] = __builtin_amdgcn_mfma_f32_16x16x32_f16(ax, bfW[nt][kt], hB[mt][nt], 0, 0, 0);
        }
    }

    // ---- silu; v -> V^T LDS (f16); qk channels kept in regs ----
    float qkv[4][4];
    #pragma unroll
    for (int mt = 0; mt < 4; ++mt) {
        float s2[4], s3[4];
        #pragma unroll
        for (int nt = 0; nt < 4; ++nt) {
            float sl[4];
            #pragma unroll
            for (int r = 0; r < 4; ++r) {
                float h = hB[mt][nt][r];
                sl[r] = h * rcpf(1.f + __expf(-h));
            }
            int ucol = t + 16 * nt;
            if (nt < 3 && ucol < UNITD) {
                u32x2 pw; pw[0] = pk2(sl[0], sl[1]); pw[1] = pk2(sl[2], sl[3]);
                *(f16x4*)(wa + swzV(ucol, (16 * mt + 4 * g) * 2)) = __builtin_bit_cast(f16x4, pw);
            }
            if (nt == 2) { s2[0]=sl[0]; s2[1]=sl[1]; s2[2]=sl[2]; s2[3]=sl[3]; }
            if (nt == 3) { s3[0]=sl[0]; s3[1]=sl[1]; s3[2]=sl[2]; s3[3]=sl[3]; }
        }
        #pragma unroll
        for (int r = 0; r < 4; ++r) qkv[mt][r] = (t >= 14) ? s2[r] : s3[r];
    }

    // ================= phase C: RoPE via table; q,k -> LDS (rows <50 only) =================
    {
        f16* Q = (f16*)(wa + QOFF);
        f16* K = (f16*)(wa + KOFF);
        const float2* rt = (const float2*)(ws + WS_ROPE);
        int d = (t >= 14) ? (t - 14) : (t + 2);
        float sqd = sq[d], oqd = oq[d], skd = sk[d], okd = ok[d];
        #pragma unroll
        for (int mt = 0; mt < 4; ++mt)
            #pragma unroll
            for (int r = 0; r < 4; ++r) {
                int seq = 16 * mt + 4 * g + r;
                float2 cn = rt[seq * 16 + d];     // (cos*0.5, sgn*sin*0.5)
                float qv = qkv[mt][r] * sqd + oqd;
                float kv = qkv[mt][r] * skd + okd;
                float qp = dmov<0xB1>(qv);        // partner (lane^1) via DPP
                float kp = dmov<0xB1>(kv);
                if (seq < SEQ) {                  // rows >=50 would overrun compacted buffers
                    Q[seq * 20 + d] = (f16)(qv * cn.x + qp * cn.y);
                    K[seq * 20 + d] = (f16)(kv * cn.x + kp * cn.y);
                }
            }
    }

    // ================= phase D: P^T = q'k'^T (0.25 baked), masked, softmax (in-register) =====
    f16x4 ak[4], bq_[4];
    #pragma unroll
    for (int m4 = 0; m4 < 4; ++m4) {
        int jr = 16 * m4 + t; if (jr > SEQ - 1) jr = SEQ - 1;   // rows >=50 mask-killed below
        ak[m4] = *(f16x4*)(wa + KOFF + jr * 40 + 8 * g);
    }
    #pragma unroll
    for (int n4 = 0; n4 < 4; ++n4) {
        int ir = 16 * n4 + t; if (ir > SEQ - 1) ir = SEQ - 1;   // cols >=50 mask-killed in H
        bq_[n4] = *(f16x4*)(wa + QOFF + ir * 40 + 8 * g);
    }

    f32x4 pT[4][4];
    #pragma unroll
    for (int m4 = 0; m4 < 4; ++m4)
        #pragma unroll
        for (int n4 = 0; n4 < 4; ++n4) {
            f32x4 z; z[0]=0.f; z[1]=0.f; z[2]=0.f; z[3]=0.f;
            pT[m4][n4] = __builtin_amdgcn_mfma_f32_16x16x16f16(ak[m4], bq_[n4], z, 0, 0, 0);
        }

    f32x4 mj4[4];
    float NBv[4][4];
    #pragma unroll
    for (int m4 = 0; m4 < 4; ++m4) {
        mj4[m4] = *(f32x4*)(M + 16 * m4 + 4 * g);
        #pragma unroll
        for (int r = 0; r < 4; ++r)
            NBv[m4][r] = fmaf(mj4[m4][r], NEGBIG, -NEGBIG);    // (m-1)*BIG
    }

    // P stays in registers as PV's B-fragments: pb[n4][m4] holds P^T[j=16m4+4g+jj][i=16n4+t]
    f16x4 pb[4][4];
    #pragma unroll
    for (int n4 = 0; n4 < 4; ++n4) {
        float a_[4][4];
        #pragma unroll
        for (int m4 = 0; m4 < 4; ++m4)
            #pragma unroll
            for (int r = 0; r < 4; ++r)
                a_[m4][r] = fmaf(pT[m4][n4][r], mj4[m4][r], NBv[m4][r]);

        float mr[4];
        #pragma unroll
        for (int m4 = 0; m4 < 4; ++m4)
            mr[m4] = fmaxf(fmaxf(a_[m4][0], a_[m4][1]), fmaxf(a_[m4][2], a_[m4][3]));
        float mx = fmaxf(fmaxf(mr[0], mr[1]), fmaxf(mr[2], mr[3]));
        mx = fmaxf(mx, __shfl_xor(mx, 16)); mx = fmaxf(mx, __shfl_xor(mx, 32));

        float sr[4];
        #pragma unroll
        for (int m4 = 0; m4 < 4; ++m4) {
            #pragma unroll
            for (int r = 0; r < 4; ++r) a_[m4][r] = __expf(a_[m4][r] - mx);
            sr[m4] = (a_[m4][0] + a_[m4][1]) + (a_[m4][2] + a_[m4][3]);
        }
        float sm = (sr[0] + sr[1]) + (sr[2] + sr[3]);
        sm += __shfl_xor(sm, 16); sm += __shfl_xor(sm, 32);
        float inv = rcpf(sm);

        #pragma unroll
        for (int m4 = 0; m4 < 4; ++m4) {
            u32x2 pw;
            pw[0] = pk2(a_[m4][0] * inv, a_[m4][1] * inv);
            pw[1] = pk2(a_[m4][2] * inv, a_[m4][3] * inv);
            pb[n4][m4] = __builtin_bit_cast(f16x4, pw);
        }
    }

    // ================= phase F: out^T = V^T @ P^T  (A from LDS, B from regs) =============
    f32x4 oT[3][4];
    #pragma unroll
    for (int nt = 0; nt < 3; ++nt)
        #pragma unroll
        for (int n4 = 0; n4 < 4; ++n4) { f32x4 z; z[0]=0.f; z[1]=0.f; z[2]=0.f; z[3]=0.f; oT[nt][n4] = z; }

    #pragma unroll
    for (int nt = 0; nt < 3; ++nt) {
        int vr = t + 16 * nt; if (vr > UNITD - 1) vr = UNITD - 1;   // clamp: u>=46 killed by Wo frag zeros
        #pragma unroll
        for (int m4 = 0; m4 < 4; ++m4) {
            f16x4 av = *(f16x4*)(wa + swzV(vr, (16 * m4 + 4 * g) * 2));
            #pragma unroll
            for (int n4 = 0; n4 < 4; ++n4)
                oT[nt][n4] = __builtin_amdgcn_mfma_f32_16x16x16f16(av, pb[n4][m4], oT[nt][n4], 0, 0, 0);
        }
    }

    // ================= phase G: out2^T = Wo @ out^T (+bo as C-init), all in-register ======
    float bov[3][4], wqv[3][4];
    #pragma unroll
    for (int mo = 0; mo < 3; ++mo)
        #pragma unroll
        for (int r = 0; r < 4; ++r) {
            int o = 16 * mo + 4 * g + r; bool ok2 = (o < UNITD);
            bov[mo][r] = ok2 ? bo[o] : 0.f;
            wqv[mo][r] = ok2 ? Wq[o] : 0.f;
        }

    f32x4 o2[3][4];
    #pragma unroll
    for (int mo = 0; mo < 3; ++mo)
        #pragma unroll
        for (int n4 = 0; n4 < 4; ++n4) {
            f32x4 c;
            #pragma unroll
            for (int r = 0; r < 4; ++r) c[r] = bov[mo][r];
            o2[mo][n4] = c;
        }

    #pragma unroll
    for (int kt2 = 0; kt2 < 3; ++kt2) {
        f16x4 awf[3];
        #pragma unroll
        for (int mo = 0; mo < 3; ++mo)
            awf[mo] = __builtin_bit_cast(f16x4, wo2[(mo * 3 + kt2) * 64 + lane]);
        #pragma unroll
        for (int n4 = 0; n4 < 4; ++n4) {
            u32x2 bw;
            bw[0] = pk2(oT[kt2][n4][0], oT[kt2][n4][1]);
            bw[1] = pk2(oT[kt2][n4][2], oT[kt2][n4][3]);
            f16x4 bof = __builtin_bit_cast(f16x4, bw);
            #pragma unroll
            for (int mo = 0; mo < 3; ++mo)
                o2[mo][n4] = __builtin_amdgcn_mfma_f32_16x16x16f16(awf[mo], bof, o2[mo][n4], 0, 0, 0);
        }
    }

    // ================= phase H: prob = softmax_i(out2 . Wq + bq, masked) =================
    float bq0 = bq[0];
    float tv[4]; float mx2 = -INFINITY;
    #pragma unroll
    for (int n4 = 0; n4 < 4; ++n4) {
        float s = 0.f;
        #pragma unroll
        for (int mo = 0; mo < 3; ++mo)
            #pragma unroll
            for (int r = 0; r < 4; ++r) s += o2[mo][n4][r] * wqv[mo][r];
        s += __shfl_xor(s, 16); s += __shfl_xor(s, 32);
        float mi = M[t + 16 * n4];
        float nb = fmaf(mi, NEGBIG, -NEGBIG);
        tv[n4] = fmaf(s + bq0, mi, nb);
        mx2 = fmaxf(mx2, tv[n4]);
    }
    mx2 = dmax16(mx2);
    float sm2 = 0.f;
    #pragma unroll
    for (int n4 = 0; n4 < 4; ++n4) { float e = __expf(tv[n4] - mx2); tv[n4] = e; sm2 += e; }
    sm2 = dsum16(sm2);
    float inv2 = rcpf(sm2);

    // ================= phase I: result[o] = sum_i out2[i][o] * prob[i] =================
    #pragma unroll
    for (int mo = 0; mo < 3; ++mo) {
        float racc[4];
        #pragma unroll
        for (int r = 0; r < 4; ++r) {
            float a = 0.f;
            #pragma unroll
            for (int n4 = 0; n4 < 4; ++n4) a += o2[mo][n4][r] * tv[n4];
            racc[r] = dsum16(a);
        }
        if (t == 0) {
            #pragma unroll
            for (int r = 0; r < 4; ++r) {
                int o = 16 * mo + 4 * g + r;
                if (o < UNITD) out[(size_t)b * UNITD + o] = racc[r] * inv2;
            }
        }
    }
}

extern "C" void kernel_launch(void* const* d_in, const int* in_sizes, int n_in,
                              void* d_out, int out_size, void* d_ws, size_t ws_size,
                              hipStream_t stream) {
    const float* x    = (const float*)d_in[0];
    const float* mask = (const float*)d_in[1];
    const float* Wi   = (const float*)d_in[2];
    const float* bi   = (const float*)d_in[3];
    const float* Wo   = (const float*)d_in[4];
    const float* bo   = (const float*)d_in[5];
    const float* sq   = (const float*)d_in[6];
    const float* oq   = (const float*)d_in[7];
    const float* sk   = (const float*)d_in[8];
    const float* ok   = (const float*)d_in[9];
    const float* Wq   = (const float*)d_in[10];
    const float* bq   = (const float*)d_in[11];
    float* outp       = (float*)d_out;

    prep_kernel<<<1, 64, 0, stream>>>(Wi, Wo, (char*)d_ws);

    const int B = in_sizes[0] / (SEQ * UNITD);
    const int blocks = (B + 3) / 4;
    gau_kernel<<<blocks, 256, 0, stream>>>(x, mask, (const char*)d_ws, bi, bo,
                                           sq, oq, sk, ok, Wq, bq, outp, B);
}